// Round 1
// baseline (493.417 us; speedup 1.0000x reference)
//
#include <hip/hip_runtime.h>
#include <math.h>

#define BB 128
#define SS 200
#define MM 50
#define DKK 64
#define DVV 128
#define FF 64
#define NROW (BB*SS)   // 25600

// workspace layout (floats)
#define W_OFF   0L
#define E_OFF   (W_OFF + (long)NROW*MM)        // 1,280,000
#define A_OFF   (E_OFF + (long)NROW*DVV)       // +3,276,800
#define R_OFF   (A_OFF + (long)NROW*DVV)
#define ACC_OFF (R_OFF + (long)NROW*DVV)       // 2 floats

// ---------------- Kernel 1: w = softmax(q_e @ mem_key^T) ----------------
// one item per thread; mem_key broadcast from LDS as float4; softmax thread-local
__global__ __launch_bounds__(64) void k_scores(const int* __restrict__ q_data,
                                               const float* __restrict__ q_embed_w,
                                               const float* __restrict__ mem_key,
                                               float* __restrict__ w_out,
                                               float* __restrict__ acc) {
    __shared__ float4 mk[MM * 16];   // 50 rows x 16 float4 = 12.8 KB
    int tid = threadIdx.x;
    const float4* mk_g = (const float4*)mem_key;
    for (int i = tid; i < MM * 16; i += 64) mk[i] = mk_g[i];
    if (blockIdx.x == 0 && tid == 0) { acc[0] = 0.f; acc[1] = 0.f; }
    __syncthreads();

    int item = blockIdx.x * 64 + tid;          // grid = 400 blocks exactly covers 25600
    int qidx = q_data[item];
    const float4* qg = (const float4*)(q_embed_w + (long)qidx * DKK);
    float4 q[16];
#pragma unroll
    for (int i = 0; i < 16; i++) q[i] = qg[i];

    float s[MM];
    float mx = -1e30f;
#pragma unroll
    for (int m = 0; m < MM; m++) {
        float a = 0.f;
#pragma unroll
        for (int k4 = 0; k4 < 16; k4++) {
            float4 mkv = mk[m * 16 + k4];
            float4 qv = q[k4];
            a = fmaf(qv.x, mkv.x, a);
            a = fmaf(qv.y, mkv.y, a);
            a = fmaf(qv.z, mkv.z, a);
            a = fmaf(qv.w, mkv.w, a);
        }
        s[m] = a;
        mx = fmaxf(mx, a);
    }
    float sum = 0.f;
#pragma unroll
    for (int m = 0; m < MM; m++) { s[m] = expf(s[m] - mx); sum += s[m]; }
    float inv = 1.f / sum;
    float* wo = w_out + (long)item * MM;
#pragma unroll
    for (int m = 0; m < MM; m++) wo[m] = s[m] * inv;
}

// ---------------- Kernel 2: e = sigmoid(qa_e@We^T+be), a = tanh(qa_e@Wa^T+ba) ----------------
// 16 rows x 128 cols per block; K chunked by 32; W chunks + qa tile in LDS (+1 pad)
__global__ __launch_bounds__(256) void k_ea(const int* __restrict__ qa_data,
                                            const float* __restrict__ qa_embed_w,
                                            const float* __restrict__ erase_w,
                                            const float* __restrict__ erase_b,
                                            const float* __restrict__ add_w,
                                            const float* __restrict__ add_b,
                                            float* __restrict__ E,
                                            float* __restrict__ A) {
    __shared__ float We[128 * 33];
    __shared__ float Wa[128 * 33];
    __shared__ float qa[16 * 33];
    __shared__ int qidx[16];
    int tid = threadIdx.x;
    int r0 = blockIdx.x * 16;
    if (tid < 16) qidx[tid] = qa_data[r0 + tid];

    int v = tid & 127, rq = tid >> 7;
    float acc_e[8], acc_a[8];
#pragma unroll
    for (int j = 0; j < 8; j++) { acc_e[j] = 0.f; acc_a[j] = 0.f; }

    for (int kc = 0; kc < 4; kc++) {
        __syncthreads();
        for (int idx = tid; idx < 4096; idx += 256) {
            int vv = idx >> 5, kk = idx & 31;
            We[vv * 33 + kk] = erase_w[vv * 128 + kc * 32 + kk];
            Wa[vv * 33 + kk] = add_w[vv * 128 + kc * 32 + kk];
        }
        for (int idx = tid; idx < 512; idx += 256) {
            int rr = idx >> 5, kk = idx & 31;
            qa[rr * 33 + kk] = qa_embed_w[(long)qidx[rr] * 128 + kc * 32 + kk];
        }
        __syncthreads();
#pragma unroll
        for (int kk = 0; kk < 32; kk++) {
            float we = We[v * 33 + kk], wa = Wa[v * 33 + kk];
#pragma unroll
            for (int j = 0; j < 8; j++) {
                float q = qa[(rq * 8 + j) * 33 + kk];
                acc_e[j] = fmaf(q, we, acc_e[j]);
                acc_a[j] = fmaf(q, wa, acc_a[j]);
            }
        }
    }
    float eb = erase_b[v], ab = add_b[v];
#pragma unroll
    for (int j = 0; j < 8; j++) {
        int r = r0 + rq * 8 + j;
        float ev = 1.f / (1.f + expf(-(acc_e[j] + eb)));
        float av = tanhf(acc_a[j] + ab);
        E[(long)r * 128 + v] = ev;
        A[(long)r * 128 + v] = av;
    }
}

// ---------------- Kernel 3: sequential memory scan ----------------
// block = one batch element (128 blocks), thread = one value-dim v (128 threads)
// Mv[:,v] (50 floats) lives in registers; w broadcast from double-buffered LDS
__global__ __launch_bounds__(128) void k_scan(const float* __restrict__ w_all,
                                              const float* __restrict__ E,
                                              const float* __restrict__ A,
                                              const float* __restrict__ init_mv,
                                              float* __restrict__ R) {
    __shared__ float wb[2][64];
    int b = blockIdx.x, v = threadIdx.x;
    float Mv[MM];
#pragma unroll
    for (int m = 0; m < MM; m++) Mv[m] = init_mv[m * DVV + v];

    const float* wrow = w_all + (long)b * SS * MM;
    const float* Eb = E + (long)b * SS * DVV + v;
    const float* Ab = A + (long)b * SS * DVV + v;
    float* Rb = R + (long)b * SS * DVV + v;

    if (v < MM) wb[0][v] = wrow[v];
    float e_cur = Eb[0], a_cur = Ab[0];
    __syncthreads();

    for (int t = 0; t < SS; t++) {
        int cur = t & 1;
        float e_nxt = 0.f, a_nxt = 0.f;
        if (t + 1 < SS) {
            if (v < MM) wb[cur ^ 1][v] = wrow[(t + 1) * MM + v];
            e_nxt = Eb[(t + 1) * DVV];
            a_nxt = Ab[(t + 1) * DVV];
        }
        float rd = 0.f;
        float e = e_cur, a = a_cur;
#pragma unroll
        for (int m = 0; m < MM; m++) {
            float wm = wb[cur][m];
            rd = fmaf(wm, Mv[m], rd);                 // read uses PRE-update Mv
            float tmp = fmaf(-e, Mv[m], a);           // a - e*Mv
            Mv[m] = fmaf(wm, tmp, Mv[m]);             // Mv + w*(a - e*Mv)
        }
        Rb[t * DVV] = rd;
        e_cur = e_nxt; a_cur = a_nxt;
        __syncthreads();
    }
}

// ---------------- Kernel 4: h = tanh([read,q_e]@read_w^T+rb); logit; BCE; probs ----------------
__global__ __launch_bounds__(256) void k_fc(const float* __restrict__ R,
                                            const int* __restrict__ q_data,
                                            const float* __restrict__ q_embed_w,
                                            const float* __restrict__ read_w,
                                            const float* __restrict__ read_b,
                                            const float* __restrict__ pred_w,
                                            const float* __restrict__ pred_b,
                                            const float* __restrict__ target,
                                            float* __restrict__ out,
                                            float* __restrict__ acc) {
    __shared__ float Wl[64 * 193];   // 49.4 KB, pad -> (f+k)%32, 2-way = free
    __shared__ float xl[32 * 192];   // 24 KB, broadcast reads
    __shared__ int qidx[32];
    int tid = threadIdx.x;
    int r0 = blockIdx.x * 32;
    if (tid < 32) qidx[tid] = q_data[r0 + tid];
    for (int idx = tid; idx < 64 * 192; idx += 256) {
        int f = idx / 192, k = idx - f * 192;
        Wl[f * 193 + k] = read_w[idx];
    }
    __syncthreads();
    for (int idx = tid; idx < 32 * 192; idx += 256) {
        int r = idx / 192, c = idx - r * 192;
        float val;
        if (c < 128) val = R[(long)(r0 + r) * 128 + c];
        else         val = q_embed_w[(long)qidx[r] * 64 + (c - 128)];
        xl[idx] = val;
    }
    __syncthreads();

    int f = tid & 63, rq = tid >> 6;
    float accv[8];
#pragma unroll
    for (int j = 0; j < 8; j++) accv[j] = 0.f;
    for (int k = 0; k < 192; k++) {
        float wv = Wl[f * 193 + k];
#pragma unroll
        for (int j = 0; j < 8; j++)
            accv[j] = fmaf(xl[(rq * 8 + j) * 192 + k], wv, accv[j]);
    }

    float rb = read_b[f], pw = pred_w[f];
    float pb = pred_b[0];
    float bce_sum = 0.f, cnt = 0.f;
    int lane = tid & 63;
#pragma unroll
    for (int j = 0; j < 8; j++) {
        float hv = tanhf(accv[j] + rb);
        float pv = pw * hv;
#pragma unroll
        for (int off = 32; off; off >>= 1) pv += __shfl_xor(pv, off, 64);
        float logit = pv + pb;
        if (lane == 0) {
            int row = r0 + rq * 8 + j;
            float tgt = target[row];
            float prob = 0.f;
            if (tgt >= 0.f) {
                prob = 1.f / (1.f + expf(-logit));
                float bce = fmaxf(logit, 0.f) - logit * tgt + log1pf(expf(-fabsf(logit)));
                bce_sum += bce;
                cnt += 1.f;
            }
            out[1 + row] = prob;
        }
    }
    if (lane == 0) {
        atomicAdd(&acc[0], bce_sum);
        atomicAdd(&acc[1], cnt);
    }
}

// ---------------- Kernel 5: finalize loss ----------------
__global__ void k_loss(const float* __restrict__ acc, float* __restrict__ out) {
    out[0] = acc[0] / fmaxf(acc[1], 1.f);
}

extern "C" void kernel_launch(void* const* d_in, const int* in_sizes, int n_in,
                              void* d_out, int out_size, void* d_ws, size_t ws_size,
                              hipStream_t stream) {
    const int*   q_data     = (const int*)d_in[0];
    const int*   qa_data    = (const int*)d_in[1];
    const float* target     = (const float*)d_in[2];
    const float* q_embed_w  = (const float*)d_in[3];
    const float* qa_embed_w = (const float*)d_in[4];
    const float* mem_key    = (const float*)d_in[5];
    const float* init_mv    = (const float*)d_in[6];
    const float* erase_w    = (const float*)d_in[7];
    const float* erase_b    = (const float*)d_in[8];
    const float* add_w      = (const float*)d_in[9];
    const float* add_b      = (const float*)d_in[10];
    const float* read_w     = (const float*)d_in[11];
    const float* read_b     = (const float*)d_in[12];
    const float* pred_w     = (const float*)d_in[13];
    const float* pred_b     = (const float*)d_in[14];
    float* out = (float*)d_out;
    float* ws  = (float*)d_ws;

    float* w_all = ws + W_OFF;
    float* E     = ws + E_OFF;
    float* A     = ws + A_OFF;
    float* R     = ws + R_OFF;
    float* acc   = ws + ACC_OFF;

    k_scores<<<NROW / 64, 64, 0, stream>>>(q_data, q_embed_w, mem_key, w_all, acc);
    k_ea<<<NROW / 16, 256, 0, stream>>>(qa_data, qa_embed_w, erase_w, erase_b,
                                        add_w, add_b, E, A);
    k_scan<<<BB, 128, 0, stream>>>(w_all, E, A, init_mv, R);
    k_fc<<<NROW / 32, 256, 0, stream>>>(R, q_data, q_embed_w, read_w, read_b,
                                        pred_w, pred_b, target, out, acc);
    k_loss<<<1, 1, 0, stream>>>(acc, out);
}

// Round 2
// 432.645 us; speedup vs baseline: 1.1405x; 1.1405x over previous
//
#include <hip/hip_runtime.h>
#include <math.h>

#define BB 128
#define SS 200
#define MM 50
#define DKK 64
#define DVV 128
#define FF 64
#define NROW (BB*SS)   // 25600

// workspace layout (floats)
#define W_OFF   0L
#define E_OFF   (W_OFF + (long)NROW*MM)
#define A_OFF   (E_OFF + (long)NROW*DVV)
#define R_OFF   (A_OFF + (long)NROW*DVV)
#define ACC_OFF (R_OFF + (long)NROW*DVV)

// ---------------- Kernel 1: w = softmax(q_e @ mem_key^T) ----------------
__global__ __launch_bounds__(64) void k_scores(const int* __restrict__ q_data,
                                               const float* __restrict__ q_embed_w,
                                               const float* __restrict__ mem_key,
                                               float* __restrict__ w_out,
                                               float* __restrict__ acc) {
    __shared__ float4 mk[MM * 16];
    int tid = threadIdx.x;
    const float4* mk_g = (const float4*)mem_key;
    for (int i = tid; i < MM * 16; i += 64) mk[i] = mk_g[i];
    if (blockIdx.x == 0 && tid == 0) { acc[0] = 0.f; acc[1] = 0.f; }
    __syncthreads();

    int item = blockIdx.x * 64 + tid;
    int qidx = q_data[item];
    const float4* qg = (const float4*)(q_embed_w + (long)qidx * DKK);
    float4 q[16];
#pragma unroll
    for (int i = 0; i < 16; i++) q[i] = qg[i];

    float s[MM];
    float mx = -1e30f;
#pragma unroll
    for (int m = 0; m < MM; m++) {
        float a = 0.f;
#pragma unroll
        for (int k4 = 0; k4 < 16; k4++) {
            float4 mkv = mk[m * 16 + k4];
            float4 qv = q[k4];
            a = fmaf(qv.x, mkv.x, a);
            a = fmaf(qv.y, mkv.y, a);
            a = fmaf(qv.z, mkv.z, a);
            a = fmaf(qv.w, mkv.w, a);
        }
        s[m] = a;
        mx = fmaxf(mx, a);
    }
    float sum = 0.f;
#pragma unroll
    for (int m = 0; m < MM; m++) { s[m] = expf(s[m] - mx); sum += s[m]; }
    float inv = 1.f / sum;
    float* wo = w_out + (long)item * MM;
#pragma unroll
    for (int m = 0; m < MM; m++) wo[m] = s[m] * inv;
}

// ---------------- Kernel 2: e/a GEMM ----------------
__global__ __launch_bounds__(256) void k_ea(const int* __restrict__ qa_data,
                                            const float* __restrict__ qa_embed_w,
                                            const float* __restrict__ erase_w,
                                            const float* __restrict__ erase_b,
                                            const float* __restrict__ add_w,
                                            const float* __restrict__ add_b,
                                            float* __restrict__ E,
                                            float* __restrict__ A) {
    __shared__ float We[128 * 33];
    __shared__ float Wa[128 * 33];
    __shared__ float qa[16 * 33];
    __shared__ int qidx[16];
    int tid = threadIdx.x;
    int r0 = blockIdx.x * 16;
    if (tid < 16) qidx[tid] = qa_data[r0 + tid];

    int v = tid & 127, rq = tid >> 7;
    float acc_e[8], acc_a[8];
#pragma unroll
    for (int j = 0; j < 8; j++) { acc_e[j] = 0.f; acc_a[j] = 0.f; }

    for (int kc = 0; kc < 4; kc++) {
        __syncthreads();
        for (int idx = tid; idx < 4096; idx += 256) {
            int vv = idx >> 5, kk = idx & 31;
            We[vv * 33 + kk] = erase_w[vv * 128 + kc * 32 + kk];
            Wa[vv * 33 + kk] = add_w[vv * 128 + kc * 32 + kk];
        }
        for (int idx = tid; idx < 512; idx += 256) {
            int rr = idx >> 5, kk = idx & 31;
            qa[rr * 33 + kk] = qa_embed_w[(long)qidx[rr] * 128 + kc * 32 + kk];
        }
        __syncthreads();
#pragma unroll
        for (int kk = 0; kk < 32; kk++) {
            float we = We[v * 33 + kk], wa = Wa[v * 33 + kk];
#pragma unroll
            for (int j = 0; j < 8; j++) {
                float q = qa[(rq * 8 + j) * 33 + kk];
                acc_e[j] = fmaf(q, we, acc_e[j]);
                acc_a[j] = fmaf(q, wa, acc_a[j]);
            }
        }
    }
    float eb = erase_b[v], ab = add_b[v];
#pragma unroll
    for (int j = 0; j < 8; j++) {
        int r = r0 + rq * 8 + j;
        float ev = 1.f / (1.f + expf(-(acc_e[j] + eb)));
        float av = tanhf(acc_a[j] + ab);
        E[(long)r * 128 + v] = ev;
        A[(long)r * 128 + v] = av;
    }
}

// ---------------- Kernel 3: sequential memory scan, wave-synchronous ----------------
// 256 blocks x 64 threads: block = (b, v_half), one WAVE per block -> zero barriers.
// Mv[:,v] (50 floats) in registers. w broadcast via v_readlane (lane m holds w[m]).
// w/e/a prefetched one step ahead in registers to hide L2/L3 latency.
__global__ __launch_bounds__(64) void k_scan(const float* __restrict__ w_all,
                                             const float* __restrict__ E,
                                             const float* __restrict__ A,
                                             const float* __restrict__ init_mv,
                                             float* __restrict__ R) {
    int b  = blockIdx.x >> 1;
    int vh = blockIdx.x & 1;
    int lane = threadIdx.x;
    int v = vh * 64 + lane;

    float Mv[MM];
#pragma unroll
    for (int m = 0; m < MM; m++) Mv[m] = init_mv[m * DVV + v];

    const float* wrow = w_all + (long)b * SS * MM;
    const float* Eb = E + (long)b * SS * DVV + v;
    const float* Ab = A + (long)b * SS * DVV + v;
    float* Rb = R + (long)b * SS * DVV + v;

    // prefetch t=0
    float wv_cur = (lane < MM) ? wrow[lane] : 0.f;
    float e_cur = Eb[0];
    float a_cur = Ab[0];

    for (int t = 0; t < SS; t++) {
        // issue prefetch for t+1 (latency hides under this step's compute)
        float wv_nxt = 0.f, e_nxt = 0.f, a_nxt = 0.f;
        if (t + 1 < SS) {
            wv_nxt = (lane < MM) ? wrow[(t + 1) * MM + lane] : 0.f;
            e_nxt = Eb[(t + 1) * DVV];
            a_nxt = Ab[(t + 1) * DVV];
        }

        float rd = 0.f;
        float e = e_cur, a = a_cur;
        unsigned wbits = __builtin_bit_cast(unsigned, wv_cur);
#pragma unroll
        for (int m = 0; m < MM; m++) {
            float wm = __builtin_bit_cast(float, __builtin_amdgcn_readlane(wbits, m));
            rd = fmaf(wm, Mv[m], rd);                 // read uses PRE-update Mv
            float tmp = fmaf(-e, Mv[m], a);           // a - e*Mv
            Mv[m] = fmaf(wm, tmp, Mv[m]);             // Mv + w*(a - e*Mv)
        }
        Rb[t * DVV] = rd;
        wv_cur = wv_nxt; e_cur = e_nxt; a_cur = a_nxt;
    }
}

// ---------------- Kernel 4: FC head + BCE ----------------
__global__ __launch_bounds__(256) void k_fc(const float* __restrict__ R,
                                            const int* __restrict__ q_data,
                                            const float* __restrict__ q_embed_w,
                                            const float* __restrict__ read_w,
                                            const float* __restrict__ read_b,
                                            const float* __restrict__ pred_w,
                                            const float* __restrict__ pred_b,
                                            const float* __restrict__ target,
                                            float* __restrict__ out,
                                            float* __restrict__ acc) {
    __shared__ float Wl[64 * 193];
    __shared__ float xl[32 * 192];
    __shared__ int qidx[32];
    int tid = threadIdx.x;
    int r0 = blockIdx.x * 32;
    if (tid < 32) qidx[tid] = q_data[r0 + tid];
    for (int idx = tid; idx < 64 * 192; idx += 256) {
        int f = idx / 192, k = idx - f * 192;
        Wl[f * 193 + k] = read_w[idx];
    }
    __syncthreads();
    for (int idx = tid; idx < 32 * 192; idx += 256) {
        int r = idx / 192, c = idx - r * 192;
        float val;
        if (c < 128) val = R[(long)(r0 + r) * 128 + c];
        else         val = q_embed_w[(long)qidx[r] * 64 + (c - 128)];
        xl[idx] = val;
    }
    __syncthreads();

    int f = tid & 63, rq = tid >> 6;
    float accv[8];
#pragma unroll
    for (int j = 0; j < 8; j++) accv[j] = 0.f;
    for (int k = 0; k < 192; k++) {
        float wv = Wl[f * 193 + k];
#pragma unroll
        for (int j = 0; j < 8; j++)
            accv[j] = fmaf(xl[(rq * 8 + j) * 192 + k], wv, accv[j]);
    }

    float rb = read_b[f], pw = pred_w[f];
    float pb = pred_b[0];
    float bce_sum = 0.f, cnt = 0.f;
    int lane = tid & 63;
#pragma unroll
    for (int j = 0; j < 8; j++) {
        float hv = tanhf(accv[j] + rb);
        float pv = pw * hv;
#pragma unroll
        for (int off = 32; off; off >>= 1) pv += __shfl_xor(pv, off, 64);
        float logit = pv + pb;
        if (lane == 0) {
            int row = r0 + rq * 8 + j;
            float tgt = target[row];
            float prob = 0.f;
            if (tgt >= 0.f) {
                prob = 1.f / (1.f + expf(-logit));
                float bce = fmaxf(logit, 0.f) - logit * tgt + log1pf(expf(-fabsf(logit)));
                bce_sum += bce;
                cnt += 1.f;
            }
            out[1 + row] = prob;
        }
    }
    if (lane == 0) {
        atomicAdd(&acc[0], bce_sum);
        atomicAdd(&acc[1], cnt);
    }
}

// ---------------- Kernel 5: finalize loss ----------------
__global__ void k_loss(const float* __restrict__ acc, float* __restrict__ out) {
    out[0] = acc[0] / fmaxf(acc[1], 1.f);
}

extern "C" void kernel_launch(void* const* d_in, const int* in_sizes, int n_in,
                              void* d_out, int out_size, void* d_ws, size_t ws_size,
                              hipStream_t stream) {
    const int*   q_data     = (const int*)d_in[0];
    const int*   qa_data    = (const int*)d_in[1];
    const float* target     = (const float*)d_in[2];
    const float* q_embed_w  = (const float*)d_in[3];
    const float* qa_embed_w = (const float*)d_in[4];
    const float* mem_key    = (const float*)d_in[5];
    const float* init_mv    = (const float*)d_in[6];
    const float* erase_w    = (const float*)d_in[7];
    const float* erase_b    = (const float*)d_in[8];
    const float* add_w      = (const float*)d_in[9];
    const float* add_b      = (const float*)d_in[10];
    const float* read_w     = (const float*)d_in[11];
    const float* read_b     = (const float*)d_in[12];
    const float* pred_w     = (const float*)d_in[13];
    const float* pred_b     = (const float*)d_in[14];
    float* out = (float*)d_out;
    float* ws  = (float*)d_ws;

    float* w_all = ws + W_OFF;
    float* E     = ws + E_OFF;
    float* A     = ws + A_OFF;
    float* R     = ws + R_OFF;
    float* acc   = ws + ACC_OFF;

    k_scores<<<NROW / 64, 64, 0, stream>>>(q_data, q_embed_w, mem_key, w_all, acc);
    k_ea<<<NROW / 16, 256, 0, stream>>>(qa_data, qa_embed_w, erase_w, erase_b,
                                        add_w, add_b, E, A);
    k_scan<<<BB * 2, 64, 0, stream>>>(w_all, E, A, init_mv, R);
    k_fc<<<NROW / 32, 256, 0, stream>>>(R, q_data, q_embed_w, read_w, read_b,
                                        pred_w, pred_b, target, out, acc);
    k_loss<<<1, 1, 0, stream>>>(acc, out);
}

// Round 3
// 421.255 us; speedup vs baseline: 1.1713x; 1.0270x over previous
//
#include <hip/hip_runtime.h>
#include <math.h>

#define BB 128
#define SS 200
#define MM 50
#define DKK 64
#define DVV 128
#define FF 64
#define NROW (BB*SS)   // 25600

// w is stored padded: 4 chunks x 16 floats (13 valid each) = 64 floats/row
#define WROW 64
#define MCH 13

// workspace layout (floats)
#define W_OFF   0L
#define E_OFF   (W_OFF + (long)NROW*WROW)
#define A_OFF   (E_OFF + (long)NROW*DVV)
#define R_OFF   (A_OFF + (long)NROW*DVV)
#define ACC_OFF (R_OFF + (long)NROW*DVV)

// ---------------- Kernel 1: w = softmax(q_e @ mem_key^T), padded layout ----------------
__global__ __launch_bounds__(64) void k_scores(const int* __restrict__ q_data,
                                               const float* __restrict__ q_embed_w,
                                               const float* __restrict__ mem_key,
                                               float* __restrict__ w_out,
                                               float* __restrict__ acc) {
    __shared__ float4 mk[MM * 16];
    int tid = threadIdx.x;
    const float4* mk_g = (const float4*)mem_key;
    for (int i = tid; i < MM * 16; i += 64) mk[i] = mk_g[i];
    if (blockIdx.x == 0 && tid == 0) { acc[0] = 0.f; acc[1] = 0.f; }
    __syncthreads();

    int item = blockIdx.x * 64 + tid;
    int qidx = q_data[item];
    const float4* qg = (const float4*)(q_embed_w + (long)qidx * DKK);
    float4 q[16];
#pragma unroll
    for (int i = 0; i < 16; i++) q[i] = qg[i];

    float s[MM];
    float mx = -1e30f;
#pragma unroll
    for (int m = 0; m < MM; m++) {
        float a = 0.f;
#pragma unroll
        for (int k4 = 0; k4 < 16; k4++) {
            float4 mkv = mk[m * 16 + k4];
            float4 qv = q[k4];
            a = fmaf(qv.x, mkv.x, a);
            a = fmaf(qv.y, mkv.y, a);
            a = fmaf(qv.z, mkv.z, a);
            a = fmaf(qv.w, mkv.w, a);
        }
        s[m] = a;
        mx = fmaxf(mx, a);
    }
    float sum = 0.f;
#pragma unroll
    for (int m = 0; m < MM; m++) { s[m] = expf(s[m] - mx); sum += s[m]; }
    float inv = 1.f / sum;
    float* wo = w_out + (long)item * WROW;
#pragma unroll
    for (int c = 0; c < 4; c++)
#pragma unroll
        for (int j = 0; j < 16; j++) {
            int m = c * MCH + j;
            wo[c * 16 + j] = (j < MCH && m < MM) ? s[m] * inv : 0.f;
        }
}

// ---------------- Kernel 2: e/a GEMM ----------------
__global__ __launch_bounds__(256) void k_ea(const int* __restrict__ qa_data,
                                            const float* __restrict__ qa_embed_w,
                                            const float* __restrict__ erase_w,
                                            const float* __restrict__ erase_b,
                                            const float* __restrict__ add_w,
                                            const float* __restrict__ add_b,
                                            float* __restrict__ E,
                                            float* __restrict__ A) {
    __shared__ float We[128 * 33];
    __shared__ float Wa[128 * 33];
    __shared__ float qa[16 * 33];
    __shared__ int qidx[16];
    int tid = threadIdx.x;
    int r0 = blockIdx.x * 16;
    if (tid < 16) qidx[tid] = qa_data[r0 + tid];

    int v = tid & 127, rq = tid >> 7;
    float acc_e[8], acc_a[8];
#pragma unroll
    for (int j = 0; j < 8; j++) { acc_e[j] = 0.f; acc_a[j] = 0.f; }

    for (int kc = 0; kc < 4; kc++) {
        __syncthreads();
        for (int idx = tid; idx < 4096; idx += 256) {
            int vv = idx >> 5, kk = idx & 31;
            We[vv * 33 + kk] = erase_w[vv * 128 + kc * 32 + kk];
            Wa[vv * 33 + kk] = add_w[vv * 128 + kc * 32 + kk];
        }
        for (int idx = tid; idx < 512; idx += 256) {
            int rr = idx >> 5, kk = idx & 31;
            qa[rr * 33 + kk] = qa_embed_w[(long)qidx[rr] * 128 + kc * 32 + kk];
        }
        __syncthreads();
#pragma unroll
        for (int kk = 0; kk < 32; kk++) {
            float we = We[v * 33 + kk], wa = Wa[v * 33 + kk];
#pragma unroll
            for (int j = 0; j < 8; j++) {
                float q = qa[(rq * 8 + j) * 33 + kk];
                acc_e[j] = fmaf(q, we, acc_e[j]);
                acc_a[j] = fmaf(q, wa, acc_a[j]);
            }
        }
    }
    float eb = erase_b[v], ab = add_b[v];
#pragma unroll
    for (int j = 0; j < 8; j++) {
        int r = r0 + rq * 8 + j;
        float ev = 1.f / (1.f + expf(-(acc_e[j] + eb)));
        float av = tanhf(acc_a[j] + ab);
        E[(long)r * 128 + v] = ev;
        A[(long)r * 128 + v] = av;
    }
}

// ---------------- Kernel 3: scan, m split 4-way across adjacent lanes ----------------
// 128 blocks x 512 threads (8 waves -> 2 waves/SIMD for latency hiding).
// tid = v*4 + mh; each thread owns 13 m-slots (padded, w=0 on pads = exact no-op).
// Read reduction = 2 intra-wave shfl_xor. Zero barriers, zero LDS.
__global__ __launch_bounds__(512) void k_scan(const float* __restrict__ w_pad,
                                              const float* __restrict__ E,
                                              const float* __restrict__ A,
                                              const float* __restrict__ init_mv,
                                              float* __restrict__ R) {
    int b = blockIdx.x;
    int tid = threadIdx.x;
    int v = tid >> 2;
    int mh = tid & 3;

    float Mv[MCH];
#pragma unroll
    for (int j = 0; j < MCH; j++) {
        int m = mh * MCH + j;
        Mv[j] = (m < MM) ? init_mv[m * DVV + v] : 0.f;
    }

    const float4* wrow = (const float4*)(w_pad + (long)b * SS * WROW + mh * 16);
    const float* Eb = E + (long)b * SS * DVV + v;
    const float* Ab = A + (long)b * SS * DVV + v;
    float* Rb = R + (long)b * SS * DVV + v;

    // prefetch t=0
    float4 w0 = wrow[0], w1 = wrow[1], w2 = wrow[2], w3 = wrow[3];
    float e_cur = Eb[0], a_cur = Ab[0];

    for (int t = 0; t < SS; t++) {
        int tn = (t + 1 < SS) ? t + 1 : t;   // clamped prefetch index (branchless)
        float4 nw0 = wrow[tn * 16 + 0];
        float4 nw1 = wrow[tn * 16 + 1];
        float4 nw2 = wrow[tn * 16 + 2];
        float4 nw3 = wrow[tn * 16 + 3];
        float e_nxt = Eb[tn * DVV];
        float a_nxt = Ab[tn * DVV];

        float wv[MCH] = {w0.x, w0.y, w0.z, w0.w,
                         w1.x, w1.y, w1.z, w1.w,
                         w2.x, w2.y, w2.z, w2.w,
                         w3.x};
        float e = e_cur, a = a_cur;
        float rd = 0.f;
#pragma unroll
        for (int j = 0; j < MCH; j++) {
            float wm = wv[j];
            rd = fmaf(wm, Mv[j], rd);                 // read uses PRE-update Mv
            float tmp = fmaf(-e, Mv[j], a);           // a - e*Mv
            Mv[j] = fmaf(wm, tmp, Mv[j]);             // Mv + w*(a - e*Mv)
        }
        rd += __shfl_xor(rd, 1, 64);
        rd += __shfl_xor(rd, 2, 64);
        if (mh == 0) Rb[t * DVV] = rd;

        w0 = nw0; w1 = nw1; w2 = nw2; w3 = nw3;
        e_cur = e_nxt; a_cur = a_nxt;
    }
}

// ---------------- Kernel 4: FC head + BCE ----------------
__global__ __launch_bounds__(256) void k_fc(const float* __restrict__ R,
                                            const int* __restrict__ q_data,
                                            const float* __restrict__ q_embed_w,
                                            const float* __restrict__ read_w,
                                            const float* __restrict__ read_b,
                                            const float* __restrict__ pred_w,
                                            const float* __restrict__ pred_b,
                                            const float* __restrict__ target,
                                            float* __restrict__ out,
                                            float* __restrict__ acc) {
    __shared__ float Wl[64 * 193];
    __shared__ float xl[32 * 192];
    __shared__ int qidx[32];
    int tid = threadIdx.x;
    int r0 = blockIdx.x * 32;
    if (tid < 32) qidx[tid] = q_data[r0 + tid];
    for (int idx = tid; idx < 64 * 192; idx += 256) {
        int f = idx / 192, k = idx - f * 192;
        Wl[f * 193 + k] = read_w[idx];
    }
    __syncthreads();
    for (int idx = tid; idx < 32 * 192; idx += 256) {
        int r = idx / 192, c = idx - r * 192;
        float val;
        if (c < 128) val = R[(long)(r0 + r) * 128 + c];
        else         val = q_embed_w[(long)qidx[r] * 64 + (c - 128)];
        xl[idx] = val;
    }
    __syncthreads();

    int f = tid & 63, rq = tid >> 6;
    float accv[8];
#pragma unroll
    for (int j = 0; j < 8; j++) accv[j] = 0.f;
    for (int k = 0; k < 192; k++) {
        float wv = Wl[f * 193 + k];
#pragma unroll
        for (int j = 0; j < 8; j++)
            accv[j] = fmaf(xl[(rq * 8 + j) * 192 + k], wv, accv[j]);
    }

    float rb = read_b[f], pw = pred_w[f];
    float pb = pred_b[0];
    float bce_sum = 0.f, cnt = 0.f;
    int lane = tid & 63;
#pragma unroll
    for (int j = 0; j < 8; j++) {
        float hv = tanhf(accv[j] + rb);
        float pv = pw * hv;
#pragma unroll
        for (int off = 32; off; off >>= 1) pv += __shfl_xor(pv, off, 64);
        float logit = pv + pb;
        if (lane == 0) {
            int row = r0 + rq * 8 + j;
            float tgt = target[row];
            float prob = 0.f;
            if (tgt >= 0.f) {
                prob = 1.f / (1.f + expf(-logit));
                float bce = fmaxf(logit, 0.f) - logit * tgt + log1pf(expf(-fabsf(logit)));
                bce_sum += bce;
                cnt += 1.f;
            }
            out[1 + row] = prob;
        }
    }
    if (lane == 0) {
        atomicAdd(&acc[0], bce_sum);
        atomicAdd(&acc[1], cnt);
    }
}

// ---------------- Kernel 5: finalize loss ----------------
__global__ void k_loss(const float* __restrict__ acc, float* __restrict__ out) {
    out[0] = acc[0] / fmaxf(acc[1], 1.f);
}

extern "C" void kernel_launch(void* const* d_in, const int* in_sizes, int n_in,
                              void* d_out, int out_size, void* d_ws, size_t ws_size,
                              hipStream_t stream) {
    const int*   q_data     = (const int*)d_in[0];
    const int*   qa_data    = (const int*)d_in[1];
    const float* target     = (const float*)d_in[2];
    const float* q_embed_w  = (const float*)d_in[3];
    const float* qa_embed_w = (const float*)d_in[4];
    const float* mem_key    = (const float*)d_in[5];
    const float* init_mv    = (const float*)d_in[6];
    const float* erase_w    = (const float*)d_in[7];
    const float* erase_b    = (const float*)d_in[8];
    const float* add_w      = (const float*)d_in[9];
    const float* add_b      = (const float*)d_in[10];
    const float* read_w     = (const float*)d_in[11];
    const float* read_b     = (const float*)d_in[12];
    const float* pred_w     = (const float*)d_in[13];
    const float* pred_b     = (const float*)d_in[14];
    float* out = (float*)d_out;
    float* ws  = (float*)d_ws;

    float* w_all = ws + W_OFF;
    float* E     = ws + E_OFF;
    float* A     = ws + A_OFF;
    float* R     = ws + R_OFF;
    float* acc   = ws + ACC_OFF;

    k_scores<<<NROW / 64, 64, 0, stream>>>(q_data, q_embed_w, mem_key, w_all, acc);
    k_ea<<<NROW / 16, 256, 0, stream>>>(qa_data, qa_embed_w, erase_w, erase_b,
                                        add_w, add_b, E, A);
    k_scan<<<BB, 512, 0, stream>>>(w_all, E, A, init_mv, R);
    k_fc<<<NROW / 32, 256, 0, stream>>>(R, q_data, q_embed_w, read_w, read_b,
                                        pred_w, pred_b, target, out, acc);
    k_loss<<<1, 1, 0, stream>>>(acc, out);
}

// Round 4
// 377.302 us; speedup vs baseline: 1.3078x; 1.1165x over previous
//
#include <hip/hip_runtime.h>
#include <math.h>

#define BB 128
#define SS 200
#define MM 50
#define DKK 64
#define DVV 128
#define FF 64
#define NROW (BB*SS)   // 25600

// w padded layout: 8 chunks x 8 floats (7 valid each): element c*8+j <-> m = c*7+j
#define WROW 64
#define MC8 7

// workspace layout (floats)
#define W_OFF   0L
#define E_OFF   (W_OFF + (long)NROW*WROW)
#define A_OFF   (E_OFF + (long)NROW*DVV)
#define R_OFF   (A_OFF + (long)NROW*DVV)
#define ACC_OFF (R_OFF + (long)NROW*DVV)

// ---------------- Kernel 1: w = softmax(q_e @ mem_key^T), padded 8x8 layout ----------------
// mem_key read directly from global with uniform addresses -> scalar loads, no LDS.
__global__ __launch_bounds__(64) void k_scores(const int* __restrict__ q_data,
                                               const float* __restrict__ q_embed_w,
                                               const float* __restrict__ mem_key,
                                               float* __restrict__ w_out,
                                               float* __restrict__ acc) {
    int tid = threadIdx.x;
    if (blockIdx.x == 0 && tid == 0) { acc[0] = 0.f; acc[1] = 0.f; }

    int item = blockIdx.x * 64 + tid;
    int qidx = q_data[item];
    const float4* qg = (const float4*)(q_embed_w + (long)qidx * DKK);
    float4 q[16];
#pragma unroll
    for (int i = 0; i < 16; i++) q[i] = qg[i];

    const float4* mk = (const float4*)mem_key;   // uniform address stream
    float s[MM];
    float mx = -1e30f;
#pragma unroll 2
    for (int m = 0; m < MM; m++) {
        float a = 0.f;
#pragma unroll
        for (int k4 = 0; k4 < 16; k4++) {
            float4 mkv = mk[m * 16 + k4];
            float4 qv = q[k4];
            a = fmaf(qv.x, mkv.x, a);
            a = fmaf(qv.y, mkv.y, a);
            a = fmaf(qv.z, mkv.z, a);
            a = fmaf(qv.w, mkv.w, a);
        }
        s[m] = a;
        mx = fmaxf(mx, a);
    }
    float sum = 0.f;
#pragma unroll
    for (int m = 0; m < MM; m++) { s[m] = expf(s[m] - mx); sum += s[m]; }
    float inv = 1.f / sum;
    float* wo = w_out + (long)item * WROW;
#pragma unroll
    for (int c = 0; c < 8; c++)
#pragma unroll
        for (int j = 0; j < 8; j++) {
            int m = c * MC8 + j;
            wo[c * 8 + j] = (j < MC8 && m < MM) ? s[m] * inv : 0.f;
        }
}

// ---------------- Kernel 2: e/a GEMM — qa rows wave-uniform via SGPR loads ----------------
// 256 threads: v = tid&127 (col), rh = tid>>7 (wave-uniform row group). 16 rows/block.
// Only We/Wa come from LDS (b128, stride 36 -> conflict-free); qa via scalar loads.
__global__ __launch_bounds__(256) void k_ea(const int* __restrict__ qa_data,
                                            const float* __restrict__ qa_embed_w,
                                            const float* __restrict__ erase_w,
                                            const float* __restrict__ erase_b,
                                            const float* __restrict__ add_w,
                                            const float* __restrict__ add_b,
                                            float* __restrict__ E,
                                            float* __restrict__ A) {
    __shared__ float Wel[128 * 36];
    __shared__ float Wal[128 * 36];
    int tid = threadIdx.x;
    int r0 = blockIdx.x * 16;
    int v = tid & 127;
    int rhu = __builtin_amdgcn_readfirstlane(tid >> 7);   // 0 or 1, wave-uniform

    const float* qrow[8];
#pragma unroll
    for (int j = 0; j < 8; j++) {
        int row = r0 + rhu * 8 + j;                        // uniform
        int idx = qa_data[row];                            // uniform -> s_load
        qrow[j] = qa_embed_w + (long)idx * DVV;
    }

    float acc_e[8], acc_a[8];
#pragma unroll
    for (int j = 0; j < 8; j++) { acc_e[j] = 0.f; acc_a[j] = 0.f; }

    for (int kc = 0; kc < 4; kc++) {
        __syncthreads();
        for (int i = tid; i < 1024; i += 256) {            // 128 rows x 8 float4
            int row = i >> 3, p = i & 7;
            float4 we = *(const float4*)(erase_w + row * 128 + kc * 32 + p * 4);
            float4 wa = *(const float4*)(add_w   + row * 128 + kc * 32 + p * 4);
            *(float4*)(&Wel[row * 36 + p * 4]) = we;
            *(float4*)(&Wal[row * 36 + p * 4]) = wa;
        }
        __syncthreads();
#pragma unroll
        for (int kk = 0; kk < 32; kk += 4) {
            float4 we4 = *(const float4*)(&Wel[v * 36 + kk]);
            float4 wa4 = *(const float4*)(&Wal[v * 36 + kk]);
#pragma unroll
            for (int j = 0; j < 8; j++) {
                float4 q4 = *(const float4*)(qrow[j] + kc * 32 + kk);   // uniform
                acc_e[j] = fmaf(q4.x, we4.x, acc_e[j]);
                acc_e[j] = fmaf(q4.y, we4.y, acc_e[j]);
                acc_e[j] = fmaf(q4.z, we4.z, acc_e[j]);
                acc_e[j] = fmaf(q4.w, we4.w, acc_e[j]);
                acc_a[j] = fmaf(q4.x, wa4.x, acc_a[j]);
                acc_a[j] = fmaf(q4.y, wa4.y, acc_a[j]);
                acc_a[j] = fmaf(q4.z, wa4.z, acc_a[j]);
                acc_a[j] = fmaf(q4.w, wa4.w, acc_a[j]);
            }
        }
    }
    float eb = erase_b[v], ab = add_b[v];
#pragma unroll
    for (int j = 0; j < 8; j++) {
        int row = r0 + rhu * 8 + j;
        float ev = 1.f / (1.f + expf(-(acc_e[j] + eb)));
        float av = tanhf(acc_a[j] + ab);
        E[(long)row * DVV + v] = ev;
        A[(long)row * DVV + v] = av;
    }
}

// ---------------- Kernel 3: scan — 256 blocks, m split 8-way, depth-4 pipeline ----------------
// block = (b, v_half): 512 threads, v = vh*64 + (tid>>3), mh = tid&7, 7 m-slots/thread.
// w/e/a prefetched 4 steps ahead in register slots; reduce = 3 shfl_xor; no LDS/barriers.
__global__ __launch_bounds__(512) void k_scan(const float* __restrict__ w_pad,
                                              const float* __restrict__ E,
                                              const float* __restrict__ A,
                                              const float* __restrict__ init_mv,
                                              float* __restrict__ R) {
    int b  = blockIdx.x >> 1;
    int vh = blockIdx.x & 1;
    int tid = threadIdx.x;
    int v = vh * 64 + (tid >> 3);
    int mh = tid & 7;

    float Mv[MC8];
#pragma unroll
    for (int j = 0; j < MC8; j++) {
        int m = mh * MC8 + j;
        Mv[j] = (m < MM) ? init_mv[m * DVV + v] : 0.f;
    }

    const float* wbase = w_pad + (long)b * SS * WROW + mh * 8;
    const float* Eb = E + (long)b * SS * DVV + v;
    const float* Ab = A + (long)b * SS * DVV + v;
    float* Rb = R + (long)b * SS * DVV + v;

    float4 wA[4], wB[4];
    float ee[4], aa[4];
#pragma unroll
    for (int d = 0; d < 4; d++) {
        wA[d] = *(const float4*)(wbase + d * WROW);
        wB[d] = *(const float4*)(wbase + d * WROW + 4);
        ee[d] = Eb[d * DVV];
        aa[d] = Ab[d * DVV];
    }

    for (int t = 0; t < SS; t += 4) {
#pragma unroll
        for (int d = 0; d < 4; d++) {
            int tc = t + d;
            float wv[8] = {wA[d].x, wA[d].y, wA[d].z, wA[d].w,
                           wB[d].x, wB[d].y, wB[d].z, wB[d].w};
            float e = ee[d], a = aa[d];
            float rd = 0.f;
#pragma unroll
            for (int j = 0; j < MC8; j++) {
                float wm = wv[j];
                rd = fmaf(wm, Mv[j], rd);                 // read uses PRE-update Mv
                float tmp = fmaf(-e, Mv[j], a);           // a - e*Mv
                Mv[j] = fmaf(wm, tmp, Mv[j]);             // Mv + w*(a - e*Mv)
            }
            rd += __shfl_xor(rd, 1, 64);
            rd += __shfl_xor(rd, 2, 64);
            rd += __shfl_xor(rd, 4, 64);
            if (mh == 0) Rb[tc * DVV] = rd;

            int tp = tc + 4; if (tp > SS - 1) tp = SS - 1;
            wA[d] = *(const float4*)(wbase + tp * WROW);
            wB[d] = *(const float4*)(wbase + tp * WROW + 4);
            ee[d] = Eb[tp * DVV];
            aa[d] = Ab[tp * DVV];
        }
    }
}

// ---------------- Kernel 4: FC head + BCE — x rows wave-uniform via SGPR loads ----------------
// 256 threads: f = tid&63, rh = tid>>6 (wave-uniform). 32 rows/block, 8 rows/thread.
// read_w staged once in LDS (stride 196, b128 conflict-free); x never touches LDS.
__global__ __launch_bounds__(256) void k_fc(const float* __restrict__ Rr,
                                            const int* __restrict__ q_data,
                                            const float* __restrict__ q_embed_w,
                                            const float* __restrict__ read_w,
                                            const float* __restrict__ read_b,
                                            const float* __restrict__ pred_w,
                                            const float* __restrict__ pred_b,
                                            const float* __restrict__ target,
                                            float* __restrict__ out,
                                            float* __restrict__ acc) {
    __shared__ float Wl[64 * 196];   // 49 KB
    int tid = threadIdx.x;
    int r0 = blockIdx.x * 32;
    int f = tid & 63;
    int rhu = __builtin_amdgcn_readfirstlane(tid >> 6);   // 0..3 wave-uniform

    for (int i = tid; i < 3072; i += 256) {               // 64 rows x 48 float4
        int row = i / 48, p = i - row * 48;
        *(float4*)(&Wl[row * 196 + p * 4]) = *(const float4*)(read_w + row * 192 + p * 4);
    }

    const float* xrow[8];
    const float* qrow[8];
#pragma unroll
    for (int j = 0; j < 8; j++) {
        int row = r0 + rhu * 8 + j;                        // uniform
        xrow[j] = Rr + (long)row * DVV;
        int qi = q_data[row];                              // uniform -> s_load
        qrow[j] = q_embed_w + (long)qi * DKK;
    }
    __syncthreads();

    float accv[8];
#pragma unroll
    for (int j = 0; j < 8; j++) accv[j] = 0.f;

#pragma unroll 4
    for (int k = 0; k < 128; k += 4) {
        float4 w4 = *(const float4*)(&Wl[f * 196 + k]);
#pragma unroll
        for (int j = 0; j < 8; j++) {
            float4 x4 = *(const float4*)(xrow[j] + k);     // uniform
            accv[j] = fmaf(x4.x, w4.x, accv[j]);
            accv[j] = fmaf(x4.y, w4.y, accv[j]);
            accv[j] = fmaf(x4.z, w4.z, accv[j]);
            accv[j] = fmaf(x4.w, w4.w, accv[j]);
        }
    }
#pragma unroll 4
    for (int k = 0; k < 64; k += 4) {
        float4 w4 = *(const float4*)(&Wl[f * 196 + 128 + k]);
#pragma unroll
        for (int j = 0; j < 8; j++) {
            float4 x4 = *(const float4*)(qrow[j] + k);     // uniform
            accv[j] = fmaf(x4.x, w4.x, accv[j]);
            accv[j] = fmaf(x4.y, w4.y, accv[j]);
            accv[j] = fmaf(x4.z, w4.z, accv[j]);
            accv[j] = fmaf(x4.w, w4.w, accv[j]);
        }
    }

    float rb = read_b[f], pw = pred_w[f];
    float pb = pred_b[0];
    float bce_sum = 0.f, cnt = 0.f;
#pragma unroll
    for (int j = 0; j < 8; j++) {
        float hv = tanhf(accv[j] + rb);
        float pv = pw * hv;
#pragma unroll
        for (int off = 32; off; off >>= 1) pv += __shfl_xor(pv, off, 64);
        float logit = pv + pb;
        if (f == 0) {
            int row = r0 + rhu * 8 + j;
            float tgt = target[row];
            float prob = 0.f;
            if (tgt >= 0.f) {
                prob = 1.f / (1.f + expf(-logit));
                float bce = fmaxf(logit, 0.f) - logit * tgt + log1pf(expf(-fabsf(logit)));
                bce_sum += bce;
                cnt += 1.f;
            }
            out[1 + row] = prob;
        }
    }
    if (f == 0) {
        atomicAdd(&acc[0], bce_sum);
        atomicAdd(&acc[1], cnt);
    }
}

// ---------------- Kernel 5: finalize loss ----------------
__global__ void k_loss(const float* __restrict__ acc, float* __restrict__ out) {
    out[0] = acc[0] / fmaxf(acc[1], 1.f);
}

extern "C" void kernel_launch(void* const* d_in, const int* in_sizes, int n_in,
                              void* d_out, int out_size, void* d_ws, size_t ws_size,
                              hipStream_t stream) {
    const int*   q_data     = (const int*)d_in[0];
    const int*   qa_data    = (const int*)d_in[1];
    const float* target     = (const float*)d_in[2];
    const float* q_embed_w  = (const float*)d_in[3];
    const float* qa_embed_w = (const float*)d_in[4];
    const float* mem_key    = (const float*)d_in[5];
    const float* init_mv    = (const float*)d_in[6];
    const float* erase_w    = (const float*)d_in[7];
    const float* erase_b    = (const float*)d_in[8];
    const float* add_w      = (const float*)d_in[9];
    const float* add_b      = (const float*)d_in[10];
    const float* read_w     = (const float*)d_in[11];
    const float* read_b     = (const float*)d_in[12];
    const float* pred_w     = (const float*)d_in[13];
    const float* pred_b     = (const float*)d_in[14];
    float* out = (float*)d_out;
    float* ws  = (float*)d_ws;

    float* w_all = ws + W_OFF;
    float* E     = ws + E_OFF;
    float* A     = ws + A_OFF;
    float* R     = ws + R_OFF;
    float* acc   = ws + ACC_OFF;

    k_scores<<<NROW / 64, 64, 0, stream>>>(q_data, q_embed_w, mem_key, w_all, acc);
    k_ea<<<NROW / 16, 256, 0, stream>>>(qa_data, qa_embed_w, erase_w, erase_b,
                                        add_w, add_b, E, A);
    k_scan<<<BB * 2, 512, 0, stream>>>(w_all, E, A, init_mv, R);
    k_fc<<<NROW / 32, 256, 0, stream>>>(R, q_data, q_embed_w, read_w, read_b,
                                        pred_w, pred_b, target, out, acc);
    k_loss<<<1, 1, 0, stream>>>(acc, out);
}

// Round 5
// 306.685 us; speedup vs baseline: 1.6089x; 1.2303x over previous
//
#include <hip/hip_runtime.h>
#include <math.h>

#define BB 128
#define SS 200
#define MM 50
#define DKK 64
#define DVV 128
#define FF 64
#define NROW (BB*SS)   // 25600

// w padded layout: 8 chunks x 8 floats (7 valid each): element c*8+j <-> m = c*7+j
#define WROW 64
#define MC8 7

// workspace layout (floats)
#define W_OFF   0L
#define E_OFF   (W_OFF + (long)NROW*WROW)
#define A_OFF   (E_OFF + (long)NROW*DVV)
#define R_OFF   (A_OFF + (long)NROW*DVV)
#define ACC_OFF (R_OFF + (long)NROW*DVV)

// ---------------- Kernel 1: w = softmax(q_e @ mem_key^T), padded 8x8 layout ----------------
// mem_key staged ONCE in LDS, read as b128 broadcasts (uniform addr within wave).
__global__ __launch_bounds__(256) void k_scores(const int* __restrict__ q_data,
                                                const float* __restrict__ q_embed_w,
                                                const float* __restrict__ mem_key,
                                                float* __restrict__ w_out,
                                                float* __restrict__ acc) {
    __shared__ float4 mk[MM * 16];   // 12.8 KB
    int tid = threadIdx.x;
    const float4* mkg = (const float4*)mem_key;
    for (int i = tid; i < MM * 16; i += 256) mk[i] = mkg[i];
    if (blockIdx.x == 0 && tid == 0) { acc[0] = 0.f; acc[1] = 0.f; }
    __syncthreads();

    int item = blockIdx.x * 256 + tid;
    int qidx = q_data[item];
    const float4* qg = (const float4*)(q_embed_w + (long)qidx * DKK);
    float4 q[16];
#pragma unroll
    for (int i = 0; i < 16; i++) q[i] = qg[i];

    float s[MM];
    float mx = -1e30f;
#pragma unroll 2
    for (int m = 0; m < MM; m++) {
        float a = 0.f;
#pragma unroll
        for (int k4 = 0; k4 < 16; k4++) {
            float4 mkv = mk[m * 16 + k4];
            float4 qv = q[k4];
            a = fmaf(qv.x, mkv.x, a);
            a = fmaf(qv.y, mkv.y, a);
            a = fmaf(qv.z, mkv.z, a);
            a = fmaf(qv.w, mkv.w, a);
        }
        s[m] = a;
        mx = fmaxf(mx, a);
    }
    float sum = 0.f;
#pragma unroll
    for (int m = 0; m < MM; m++) { s[m] = expf(s[m] - mx); sum += s[m]; }
    float inv = 1.f / sum;

    float4* wo4 = (float4*)(w_out + (long)item * WROW);
#pragma unroll
    for (int c = 0; c < 8; c++) {
        float4 lo, hi;
        lo.x = (c * 7 + 0 < MM) ? s[c * 7 + 0] * inv : 0.f;
        lo.y = (c * 7 + 1 < MM) ? s[c * 7 + 1] * inv : 0.f;
        lo.z = (c * 7 + 2 < MM) ? s[c * 7 + 2] * inv : 0.f;
        lo.w = (c * 7 + 3 < MM) ? s[c * 7 + 3] * inv : 0.f;
        hi.x = (c * 7 + 4 < MM) ? s[c * 7 + 4] * inv : 0.f;
        hi.y = (c * 7 + 5 < MM) ? s[c * 7 + 5] * inv : 0.f;
        hi.z = (c * 7 + 6 < MM) ? s[c * 7 + 6] * inv : 0.f;
        hi.w = 0.f;   // pad slot
        wo4[c * 2]     = lo;
        wo4[c * 2 + 1] = hi;
    }
}

// ---------------- Kernel 2: e/a GEMM — 32 rows x 128 v per block ----------------
// thread: vq=tid&31 owns v in {vq,vq+32,vq+64,vq+96}; rh=tid>>5 owns 4 rows.
// Per k4: 8 W-b128 + 4 x-b128 -> 128 FMA. Strides 68 (2-way = free). 78 KB LDS -> 2 blk/CU.
__global__ __launch_bounds__(256) void k_ea(const int* __restrict__ qa_data,
                                            const float* __restrict__ qa_embed_w,
                                            const float* __restrict__ erase_w,
                                            const float* __restrict__ erase_b,
                                            const float* __restrict__ add_w,
                                            const float* __restrict__ add_b,
                                            float* __restrict__ E,
                                            float* __restrict__ A) {
    __shared__ float Wel[128 * 68];
    __shared__ float Wal[128 * 68];
    __shared__ float xl[32 * 68];
    int tid = threadIdx.x;
    int r0 = blockIdx.x * 32;
    int vq = tid & 31;
    int rh = tid >> 5;   // 0..7

    float acc_e[4][4], acc_a[4][4];
#pragma unroll
    for (int i = 0; i < 4; i++)
#pragma unroll
        for (int j = 0; j < 4; j++) { acc_e[i][j] = 0.f; acc_a[i][j] = 0.f; }

    for (int kc = 0; kc < 2; kc++) {
        __syncthreads();
        for (int i = tid; i < 4096; i += 256) {          // 2 mats x 128 v x 16 float4
            int mat = i >> 11;
            int r = (i >> 4) & 127, p = i & 15;
            const float* src = (mat ? add_w : erase_w) + r * 128 + kc * 64 + p * 4;
            float* dst = (mat ? Wal : Wel) + r * 68 + p * 4;
            *(float4*)dst = *(const float4*)src;
        }
        for (int i = tid; i < 512; i += 256) {           // 32 rows x 16 float4
            int r = i >> 4, p = i & 15;
            int idx = qa_data[r0 + r];
            *(float4*)(xl + r * 68 + p * 4) =
                *(const float4*)(qa_embed_w + (long)idx * DVV + kc * 64 + p * 4);
        }
        __syncthreads();
#pragma unroll 4
        for (int kk = 0; kk < 64; kk += 4) {
            float4 we[4], wa[4], x4[4];
#pragma unroll
            for (int i = 0; i < 4; i++) {
                we[i] = *(const float4*)(Wel + (vq + 32 * i) * 68 + kk);
                wa[i] = *(const float4*)(Wal + (vq + 32 * i) * 68 + kk);
            }
#pragma unroll
            for (int j = 0; j < 4; j++)
                x4[j] = *(const float4*)(xl + (rh * 4 + j) * 68 + kk);
#pragma unroll
            for (int i = 0; i < 4; i++)
#pragma unroll
                for (int j = 0; j < 4; j++) {
                    acc_e[i][j] = fmaf(x4[j].x, we[i].x, acc_e[i][j]);
                    acc_e[i][j] = fmaf(x4[j].y, we[i].y, acc_e[i][j]);
                    acc_e[i][j] = fmaf(x4[j].z, we[i].z, acc_e[i][j]);
                    acc_e[i][j] = fmaf(x4[j].w, we[i].w, acc_e[i][j]);
                    acc_a[i][j] = fmaf(x4[j].x, wa[i].x, acc_a[i][j]);
                    acc_a[i][j] = fmaf(x4[j].y, wa[i].y, acc_a[i][j]);
                    acc_a[i][j] = fmaf(x4[j].z, wa[i].z, acc_a[i][j]);
                    acc_a[i][j] = fmaf(x4[j].w, wa[i].w, acc_a[i][j]);
                }
        }
    }
#pragma unroll
    for (int i = 0; i < 4; i++) {
        int v = vq + 32 * i;
        float eb = erase_b[v], ab = add_b[v];
#pragma unroll
        for (int j = 0; j < 4; j++) {
            int row = r0 + rh * 4 + j;
            E[(long)row * DVV + v] = 1.f / (1.f + expf(-(acc_e[i][j] + eb)));
            A[(long)row * DVV + v] = tanhf(acc_a[i][j] + ab);
        }
    }
}

// ---------------- Kernel 3: scan — 256 blocks, m split 8-way, depth-4 pipeline ----------------
__global__ __launch_bounds__(512) void k_scan(const float* __restrict__ w_pad,
                                              const float* __restrict__ E,
                                              const float* __restrict__ A,
                                              const float* __restrict__ init_mv,
                                              float* __restrict__ R) {
    int b  = blockIdx.x >> 1;
    int vh = blockIdx.x & 1;
    int tid = threadIdx.x;
    int v = vh * 64 + (tid >> 3);
    int mh = tid & 7;

    float Mv[MC8];
#pragma unroll
    for (int j = 0; j < MC8; j++) {
        int m = mh * MC8 + j;
        Mv[j] = (m < MM) ? init_mv[m * DVV + v] : 0.f;
    }

    const float* wbase = w_pad + (long)b * SS * WROW + mh * 8;
    const float* Eb = E + (long)b * SS * DVV + v;
    const float* Ab = A + (long)b * SS * DVV + v;
    float* Rb = R + (long)b * SS * DVV + v;

    float4 wA[4], wB[4];
    float ee[4], aa[4];
#pragma unroll
    for (int d = 0; d < 4; d++) {
        wA[d] = *(const float4*)(wbase + d * WROW);
        wB[d] = *(const float4*)(wbase + d * WROW + 4);
        ee[d] = Eb[d * DVV];
        aa[d] = Ab[d * DVV];
    }

    for (int t = 0; t < SS; t += 4) {
#pragma unroll
        for (int d = 0; d < 4; d++) {
            int tc = t + d;
            float wv[8] = {wA[d].x, wA[d].y, wA[d].z, wA[d].w,
                           wB[d].x, wB[d].y, wB[d].z, wB[d].w};
            float e = ee[d], a = aa[d];
            float rd = 0.f;
#pragma unroll
            for (int j = 0; j < MC8; j++) {
                float wm = wv[j];
                rd = fmaf(wm, Mv[j], rd);
                float tmp = fmaf(-e, Mv[j], a);
                Mv[j] = fmaf(wm, tmp, Mv[j]);
            }
            rd += __shfl_xor(rd, 1, 64);
            rd += __shfl_xor(rd, 2, 64);
            rd += __shfl_xor(rd, 4, 64);
            if (mh == 0) Rb[tc * DVV] = rd;

            int tp = tc + 4; if (tp > SS - 1) tp = SS - 1;
            wA[d] = *(const float4*)(wbase + tp * WROW);
            wB[d] = *(const float4*)(wbase + tp * WROW + 4);
            ee[d] = Eb[tp * DVV];
            aa[d] = Ab[tp * DVV];
        }
    }
}

// ---------------- Kernel 4: FC head + BCE — 64 rows x 64 f per block ----------------
// thread: fq=tid&15 owns f in {fq,fq+16,fq+32,fq+48}; rh=tid>>4 owns 4 rows.
// W (stride 196) staged once; x = [R || q_e] (stride 100) chunked K=96. 76 KB LDS.
__global__ __launch_bounds__(256) void k_fc(const float* __restrict__ Rr,
                                            const int* __restrict__ q_data,
                                            const float* __restrict__ q_embed_w,
                                            const float* __restrict__ read_w,
                                            const float* __restrict__ read_b,
                                            const float* __restrict__ pred_w,
                                            const float* __restrict__ pred_b,
                                            const float* __restrict__ target,
                                            float* __restrict__ out,
                                            float* __restrict__ acc) {
    __shared__ float Wl[64 * 196];   // 50.2 KB
    __shared__ float xl[64 * 100];   // 25.6 KB
    int tid = threadIdx.x;
    int r0 = blockIdx.x * 64;
    int fq = tid & 15;
    int rh = tid >> 4;   // 0..15

    for (int i = tid; i < 3072; i += 256) {   // 64 f x 48 float4, once
        int f = i / 48, p = i - f * 48;
        *(float4*)(Wl + f * 196 + p * 4) = *(const float4*)(read_w + f * 192 + p * 4);
    }

    float accv[4][4];
#pragma unroll
    for (int i = 0; i < 4; i++)
#pragma unroll
        for (int j = 0; j < 4; j++) accv[i][j] = 0.f;

    for (int kc = 0; kc < 2; kc++) {
        __syncthreads();
        for (int i = tid; i < 1536; i += 256) {   // 64 rows x 24 float4
            int r = i / 24, p = i - r * 24;
            float4 val;
            if (kc == 0) {
                val = *(const float4*)(Rr + (long)(r0 + r) * DVV + p * 4);
            } else if (p < 8) {
                val = *(const float4*)(Rr + (long)(r0 + r) * DVV + 96 + p * 4);
            } else {
                int qi = q_data[r0 + r];
                val = *(const float4*)(q_embed_w + (long)qi * DKK + (p - 8) * 4);
            }
            *(float4*)(xl + r * 100 + p * 4) = val;
        }
        __syncthreads();
#pragma unroll 4
        for (int kk = 0; kk < 96; kk += 4) {
            float4 wv[4], x4[4];
#pragma unroll
            for (int i = 0; i < 4; i++)
                wv[i] = *(const float4*)(Wl + (fq + 16 * i) * 196 + kc * 96 + kk);
#pragma unroll
            for (int j = 0; j < 4; j++)
                x4[j] = *(const float4*)(xl + (rh * 4 + j) * 100 + kk);
#pragma unroll
            for (int i = 0; i < 4; i++)
#pragma unroll
                for (int j = 0; j < 4; j++) {
                    accv[i][j] = fmaf(x4[j].x, wv[i].x, accv[i][j]);
                    accv[i][j] = fmaf(x4[j].y, wv[i].y, accv[i][j]);
                    accv[i][j] = fmaf(x4[j].z, wv[i].z, accv[i][j]);
                    accv[i][j] = fmaf(x4[j].w, wv[i].w, accv[i][j]);
                }
        }
    }

    float pb = pred_b[0];
    float rb_[4], pw_[4];
#pragma unroll
    for (int i = 0; i < 4; i++) { rb_[i] = read_b[fq + 16 * i]; pw_[i] = pred_w[fq + 16 * i]; }

    float bce_sum = 0.f, cnt = 0.f;
#pragma unroll
    for (int j = 0; j < 4; j++) {
        float pv = 0.f;
#pragma unroll
        for (int i = 0; i < 4; i++)
            pv = fmaf(pw_[i], tanhf(accv[i][j] + rb_[i]), pv);
        pv += __shfl_xor(pv, 1, 64);
        pv += __shfl_xor(pv, 2, 64);
        pv += __shfl_xor(pv, 4, 64);
        pv += __shfl_xor(pv, 8, 64);
        if (fq == 0) {
            int row = r0 + rh * 4 + j;
            float tgt = target[row];
            float logit = pv + pb;
            float prob = 0.f;
            if (tgt >= 0.f) {
                prob = 1.f / (1.f + expf(-logit));
                float bce = fmaxf(logit, 0.f) - logit * tgt + log1pf(expf(-fabsf(logit)));
                bce_sum += bce;
                cnt += 1.f;
            }
            out[1 + row] = prob;
        }
    }
    if (fq == 0) {
        atomicAdd(&acc[0], bce_sum);
        atomicAdd(&acc[1], cnt);
    }
}

// ---------------- Kernel 5: finalize loss ----------------
__global__ void k_loss(const float* __restrict__ acc, float* __restrict__ out) {
    out[0] = acc[0] / fmaxf(acc[1], 1.f);
}

extern "C" void kernel_launch(void* const* d_in, const int* in_sizes, int n_in,
                              void* d_out, int out_size, void* d_ws, size_t ws_size,
                              hipStream_t stream) {
    const int*   q_data     = (const int*)d_in[0];
    const int*   qa_data    = (const int*)d_in[1];
    const float* target     = (const float*)d_in[2];
    const float* q_embed_w  = (const float*)d_in[3];
    const float* qa_embed_w = (const float*)d_in[4];
    const float* mem_key    = (const float*)d_in[5];
    const float* init_mv    = (const float*)d_in[6];
    const float* erase_w    = (const float*)d_in[7];
    const float* erase_b    = (const float*)d_in[8];
    const float* add_w      = (const float*)d_in[9];
    const float* add_b      = (const float*)d_in[10];
    const float* read_w     = (const float*)d_in[11];
    const float* read_b     = (const float*)d_in[12];
    const float* pred_w     = (const float*)d_in[13];
    const float* pred_b     = (const float*)d_in[14];
    float* out = (float*)d_out;
    float* ws  = (float*)d_ws;

    float* w_all = ws + W_OFF;
    float* E     = ws + E_OFF;
    float* A     = ws + A_OFF;
    float* R     = ws + R_OFF;
    float* acc   = ws + ACC_OFF;

    k_scores<<<NROW / 256, 256, 0, stream>>>(q_data, q_embed_w, mem_key, w_all, acc);
    k_ea<<<NROW / 32, 256, 0, stream>>>(qa_data, qa_embed_w, erase_w, erase_b,
                                        add_w, add_b, E, A);
    k_scan<<<BB * 2, 512, 0, stream>>>(w_all, E, A, init_mv, R);
    k_fc<<<NROW / 64, 256, 0, stream>>>(R, q_data, q_embed_w, read_w, read_b,
                                        pred_w, pred_b, target, out, acc);
    k_loss<<<1, 1, 0, stream>>>(acc, out);
}